// Round 3
// baseline (67.870 us; speedup 1.0000x reference)
//
#include <hip/hip_runtime.h>

#define N_ELEM (1 << 20)
#define K 256
#define BLOCK 256
#define EPT 4
#define GRID (N_ELEM / (BLOCK * EPT))   // 1024 blocks -> 4 blocks/CU, 16 waves/CU

// d_ws layout: float sorted_val[256] | float2 sorted_pair[256] {val, idx_bits}

// Rank sort: thread t's center goes to slot rank(t); stable (ties by orig idx).
__global__ __launch_bounds__(K) void sort_centers_kernel(
    const float*  __restrict__ centers,
    float*        __restrict__ ws_val,
    float2*       __restrict__ ws_pair)
{
    __shared__ float sc[K];
    const int t = threadIdx.x;
    const float c = centers[t];
    sc[t] = c;
    __syncthreads();

    int rank = 0;
#pragma unroll 16
    for (int j = 0; j < K; ++j) {
        float cj = sc[j];
        rank += (cj < c) || (cj == c && j < t);
    }
    ws_val[rank]  = c;
    ws_pair[rank] = make_float2(c, __int_as_float(t));  // idx as raw bits (no arith touches it)
}

__global__ __launch_bounds__(BLOCK) void argmin_bsearch_kernel(
    const float*  __restrict__ x,
    const float*  __restrict__ ws_val,
    const float2* __restrict__ ws_pair,
    int*          __restrict__ out)
{
    __shared__ float s_val[K];
    __shared__ alignas(8) float2 s_pair[K];
    const int t = threadIdx.x;
    s_val[t]  = ws_val[t];
    s_pair[t] = ws_pair[t];      // one ds_write_b64 per thread
    __syncthreads();

    // Levels 0-2 probe at most 7 distinct, wave-uniform indices -> scalar loads
    const float v127 = ws_val[127];
    const float v63  = ws_val[63],  v191 = ws_val[191];
    const float v31  = ws_val[31],  v95  = ws_val[95];
    const float v159 = ws_val[159], v223 = ws_val[223];

    const int base = (blockIdx.x * BLOCK + t) * EPT;
    float4 v = *reinterpret_cast<const float4*>(x + base);
    float xs[EPT] = {v.x, v.y, v.z, v.w};
    int res[EPT];

#pragma unroll
    for (int e = 0; e < EPT; ++e) {
        const float xv = xs[e];

        // branchless lower_bound (pos = #centers < xv); levels s=128,64,32 in regs
        int pos = (v127 < xv) ? 128 : 0;                       // probe idx 127
        const float la = (pos & 128) ? v191 : v63;             // probe idx pos+63
        pos += (la < xv) ? 64 : 0;
        const float lb = (pos & 64) ? ((pos & 128) ? v223 : v95)
                                    : ((pos & 128) ? v159 : v31);  // probe idx pos+31
        pos += (lb < xv) ? 32 : 0;

        // levels s=16..1 + final bump via LDS (6 dependent probes)
#pragma unroll
        for (int s = 16; s > 0; s >>= 1)
            pos += (s_val[pos + s - 1] < xv) ? s : 0;          // pos <= 255 after loop
        pos += (s_val[pos] < xv) ? 1 : 0;                      // pos in [0,256]

        // nearest is a straddling neighbor; exact tie -> smaller original index
        const int il = (pos > 0) ? pos - 1 : 0;
        const int ir = (pos < K) ? pos     : K - 1;
        const float2 pl = s_pair[il];                          // ds_read_b64
        const float2 pr = s_pair[ir];                          // ds_read_b64
        const float dl = fabsf(xv - pl.x);
        const float dr = fabsf(xv - pr.x);
        const int ol  = __float_as_int(pl.y);
        const int orr = __float_as_int(pr.y);
        res[e] = (dl < dr) ? ol : ((dr < dl) ? orr : min(ol, orr));
    }

    *reinterpret_cast<int4*>(out + base) = make_int4(res[0], res[1], res[2], res[3]);
}

extern "C" void kernel_launch(void* const* d_in, const int* in_sizes, int n_in,
                              void* d_out, int out_size, void* d_ws, size_t ws_size,
                              hipStream_t stream)
{
    const float* x       = (const float*)d_in[0];
    const float* centers = (const float*)d_in[1];
    int*         out     = (int*)d_out;

    float*  ws_val  = (float*)d_ws;
    float2* ws_pair = (float2*)(ws_val + K);   // 8-byte aligned (256 floats = 1 KB offset)

    sort_centers_kernel<<<1, K, 0, stream>>>(centers, ws_val, ws_pair);
    argmin_bsearch_kernel<<<GRID, BLOCK, 0, stream>>>(x, ws_val, ws_pair, out);
}